// Round 1
// 114.588 us; speedup vs baseline: 1.0028x; 1.0028x over previous
//
#include <hip/hip_runtime.h>
#include <stdint.h>

// Two-kernel binary-morphology skeleton (R8 structure + DPP-shift morph).
// Pack: float4 loads (all 4 issued up-front) + nibble + shfl_xor OR-reduce.
// Morph: wave-autonomous REGISTER morphology — lane i holds rows 2i,2i+1 x
// 3 u64 words (center output word + halo word each side; horizontal reach
// is only +/-17px). Vertical neighbors via DPP wave_shr1/wave_shl1 (1-cycle
// VALU, zero-fill at wave edge) instead of ds_bpermute-based __shfl: the
// 8-step chain has ~192 dependent lane+/-1 exchanges on its critical path
// and only ~11 waves/CU to hide them. 1-wave blocks (64 thr) remove the
// 4-wave-block scheduling quantization tail (2816 blocks = 11/CU exactly).

typedef unsigned long long u64;
typedef float vfloat4 __attribute__((ext_vector_type(4)));

#define WIDTH   1024
#define HEIGHT  1024
#define NIMG    16
#define WPR     16          // u64 words per image row
#define RPL     2           // rows per lane
#define VROWS   128         // rows covered per wave = 64*RPL
#define HALO    17          // 8 steps x (erode+dilate) + iso conv
#define BVALID  94          // VROWS - 2*HALO
#define NBANDS  11          // ceil(1024/94)
#define PACK_ROWS 4

// ---------------- phase 1: binarize + bit-pack, float4 + shfl assembly -------
__global__ __launch_bounds__(256) void pack_kernel(const float* __restrict__ x,
                                                   u64* __restrict__ packed) {
    int wv = threadIdx.x >> 6, lane = threadIdx.x & 63;
    int row = blockIdx.x * PACK_ROWS + wv;        // one image row per wave
    const float* rbase = x + (size_t)row * WIDTH;
    u64* pbase = packed + (size_t)row * WPR;
    vfloat4 v[4];
    #pragma unroll
    for (int rnd = 0; rnd < 4; ++rnd)             // all 4 loads outstanding
        v[rnd] = *(const vfloat4*)(rbase + rnd * 256 + lane * 4);
    #pragma unroll
    for (int rnd = 0; rnd < 4; ++rnd) {           // 256 px per round
        unsigned nib = (v[rnd].x > 0.5f ? 1u : 0u) | (v[rnd].y > 0.5f ? 2u : 0u)
                     | (v[rnd].z > 0.5f ? 4u : 0u) | (v[rnd].w > 0.5f ? 8u : 0u);
        u64 n = (u64)nib << (4 * (lane & 15));
        n |= __shfl_xor(n, 1);                    // OR-reduce within 16-lane
        n |= __shfl_xor(n, 2);                    // groups: group g holds
        n |= __shfl_xor(n, 4);                    // px 256*rnd+64g..+63
        n |= __shfl_xor(n, 8);
        if ((lane & 15) == 0) pbase[rnd * 4 + (lane >> 4)] = n;
    }
}

// ---------------- wave-edge shifts via DPP (zero beyond wave = halo pad) -----
// WAVE_SHR1 (0x138): dst[i] = src[i-1]  -> value from lane above (sh_up)
// WAVE_SHL1 (0x130): dst[i] = src[i+1]  -> value from lane below (sh_dn)
// bound_ctrl=true: out-of-range source reads 0 (matches zero-pad semantics).
__device__ __forceinline__ u64 sh_up(u64 x, int lane) {
    (void)lane;
    unsigned lo = (unsigned)__builtin_amdgcn_update_dpp(
        0, (int)(unsigned)x, 0x138, 0xf, 0xf, true);
    unsigned hi = (unsigned)__builtin_amdgcn_update_dpp(
        0, (int)(unsigned)(x >> 32), 0x138, 0xf, 0xf, true);
    return ((u64)hi << 32) | lo;
}
__device__ __forceinline__ u64 sh_dn(u64 x, int lane) {
    (void)lane;
    unsigned lo = (unsigned)__builtin_amdgcn_update_dpp(
        0, (int)(unsigned)x, 0x130, 0xf, 0xf, true);
    unsigned hi = (unsigned)__builtin_amdgcn_update_dpp(
        0, (int)(unsigned)(x >> 32), 0x130, 0xf, 0xf, true);
    return ((u64)hi << 32) | lo;
}

// One skeleton step, fully in registers. Bit (LSB) = leftmost pixel.
// hand: CM&1 -> sample x-1 = (c<<1)|(left>>63); vand: RM&1 -> row above.
// Dilate uses reflected kernel (offsets negated). Proven mapping from R6/R8.
template <int RM, int CM, bool DIL>
__device__ __forceinline__ void mstep(u64 (&B)[RPL][3], u64 (&O)[RPL][3], int lane) {
    u64 T[RPL][3], M[RPL][3];
    // horizontal erode
    #pragma unroll
    for (int s = 0; s < RPL; ++s) {
        #pragma unroll
        for (int j = 0; j < 3; ++j) {
            u64 c = B[s][j], res = ~0ULL;
            if (CM & 2) res &= c;
            if (CM & 1) res &= (c << 1) | ((j > 0 ? B[s][j - 1] : 0ULL) >> 63);
            if (CM & 4) res &= (c >> 1) | ((j < 2 ? B[s][j + 1] : 0ULL) << 63);
            T[s][j] = res;
        }
    }
    // vertical erode -> M, O
    #pragma unroll
    for (int j = 0; j < 3; ++j) {
        u64 up = sh_up(T[RPL - 1][j], lane);
        u64 dn = sh_dn(T[0][j], lane);
        #pragma unroll
        for (int s = 0; s < RPL; ++s) {
            u64 res = ~0ULL;
            if (RM & 2) res &= T[s][j];
            if (RM & 1) res &= (s > 0 ? T[s - 1][j] : up);
            if (RM & 4) res &= (s < RPL - 1 ? T[s + 1][j] : dn);
            M[s][j] = res;
            O[s][j] |= res;
        }
    }
    if (DIL) {
        // horizontal dilate (reflected)
        #pragma unroll
        for (int s = 0; s < RPL; ++s) {
            #pragma unroll
            for (int j = 0; j < 3; ++j) {
                u64 c = M[s][j], res = 0;
                if (CM & 2) res |= c;
                if (CM & 1) res |= (c >> 1) | ((j < 2 ? M[s][j + 1] : 0ULL) << 63);
                if (CM & 4) res |= (c << 1) | ((j > 0 ? M[s][j - 1] : 0ULL) >> 63);
                T[s][j] = res;
            }
        }
        // vertical dilate (reflected), subtract from B
        #pragma unroll
        for (int j = 0; j < 3; ++j) {
            u64 up = sh_up(T[RPL - 1][j], lane);
            u64 dn = sh_dn(T[0][j], lane);
            #pragma unroll
            for (int s = 0; s < RPL; ++s) {
                u64 res = 0;
                if (RM & 2) res |= T[s][j];
                if (RM & 1) res |= (s < RPL - 1 ? T[s + 1][j] : dn);
                if (RM & 4) res |= (s > 0 ? T[s - 1][j] : up);
                B[s][j] &= ~res;
            }
        }
    }
}

// ---------------- phase 2: register morphology + isolated-point + expand -----
__global__ __launch_bounds__(64) void regmorph_kernel(const u64* __restrict__ packed,
                                                      float* __restrict__ out) {
    __shared__ u64 stage[BVALID + 2];
    int lane = threadIdx.x & 63;
    int W = blockIdx.x;                           // flat wave id, 0..2815
    int img  = W / (WPR * NBANDS);
    int rem  = W % (WPR * NBANDS);
    int wcol = rem / NBANDS;
    int band = rem % NBANDS;
    int bstart = band * BVALID - HALO;            // global row of v=0

    // load 2 rows x 3 words per lane, zero outside image (zero-pad semantics)
    const u64* pimg = packed + (size_t)img * HEIGHT * WPR;
    u64 B[RPL][3], O[RPL][3];
    #pragma unroll
    for (int s = 0; s < RPL; ++s) {
        int g = bstart + lane * RPL + s;
        bool rok = (g >= 0 && g < HEIGHT);
        #pragma unroll
        for (int j = 0; j < 3; ++j) {
            int wi = wcol - 1 + j;
            B[s][j] = (rok && wi >= 0 && wi < WPR) ? pimg[(size_t)g * WPR + wi] : 0ULL;
            O[s][j] = 0ULL;
        }
    }

    // 8 structuring elements as (rowmask, colmask) rectangles
    mstep<7, 7, true >(B, O, lane);   // all ones
    mstep<7, 6, true >(B, O, lane);   // cols {1,2}
    mstep<3, 7, true >(B, O, lane);   // rows {0,1}
    mstep<6, 6, true >(B, O, lane);   // rows {1,2} x cols {1,2}
    mstep<7, 2, true >(B, O, lane);   // col {1}
    mstep<2, 7, true >(B, O, lane);   // row {1}
    mstep<3, 2, true >(B, O, lane);   // col {1}, rows {0,1}
    mstep<2, 3, false>(B, O, lane);   // row {1}, cols {0,1}; B unused after

    // isolated-point: 3x3 popcount of O == 1, center word only (carry-save)
    u64 Wn[RPL], Cn[RPL], En[RPL], res[RPL];
    #pragma unroll
    for (int s = 0; s < RPL; ++s) {
        Cn[s] = O[s][1];
        Wn[s] = (O[s][1] << 1) | (O[s][0] >> 63);
        En[s] = (O[s][1] >> 1) | (O[s][2] << 63);
    }
    u64 upW = sh_up(Wn[RPL - 1], lane), upC = sh_up(Cn[RPL - 1], lane),
        upE = sh_up(En[RPL - 1], lane);
    u64 dnW = sh_dn(Wn[0], lane), dnC = sh_dn(Cn[0], lane), dnE = sh_dn(En[0], lane);
    #pragma unroll
    for (int s = 0; s < RPL; ++s) {
        u64 ones = 0, twos = 0;
        auto acc = [&](u64 v) { twos |= ones & v; ones ^= v; };
        acc(s > 0 ? Wn[s - 1] : upW);
        acc(s > 0 ? Cn[s - 1] : upC);
        acc(s > 0 ? En[s - 1] : upE);
        acc(Wn[s]); acc(Cn[s]); acc(En[s]);
        acc(s < RPL - 1 ? Wn[s + 1] : dnW);
        acc(s < RPL - 1 ? Cn[s + 1] : dnC);
        acc(s < RPL - 1 ? En[s + 1] : dnE);
        res[s] = ones & ~twos;
    }

    // stage valid rows (v in [HALO, HALO+BVALID)) into LDS
    #pragma unroll
    for (int s = 0; s < RPL; ++s) {
        int v = lane * RPL + s;
        if (v >= HALO && v < HALO + BVALID) stage[v - HALO] = res[s];
    }
    __syncthreads();   // single-wave block: cheap, orders LDS writes->reads

    // expand to f32, coalesced: per instr 4 rows x 16 lanes x 16 B (full lines)
    int gbase = band * BVALID;
    float* obase = out + (size_t)img * HEIGHT * WIDTH + wcol * 64 + (lane & 15) * 4;
    for (int it = 0; it < (BVALID + 3) / 4; ++it) {
        int t = it * 4 + (lane >> 4);
        int g = gbase + t;
        if (t < BVALID && g < HEIGHT) {
            u64 word = stage[t];
            unsigned nib = (unsigned)(word >> ((lane & 15) * 4)) & 15u;
            vfloat4 v4;
            v4.x = (nib & 1) ? 1.f : 0.f;
            v4.y = (nib & 2) ? 1.f : 0.f;
            v4.z = (nib & 4) ? 1.f : 0.f;
            v4.w = (nib & 8) ? 1.f : 0.f;
            __builtin_nontemporal_store(v4, (vfloat4*)(obase + (size_t)g * WIDTH));
        }
    }
}

extern "C" void kernel_launch(void* const* d_in, const int* in_sizes, int n_in,
                              void* d_out, int out_size, void* d_ws, size_t ws_size,
                              hipStream_t stream) {
    const float* x = (const float*)d_in[0];
    float* out = (float*)d_out;
    u64* packed = (u64*)d_ws;   // NIMG*HEIGHT*WPR*8 = 2 MiB used

    hipLaunchKernelGGL(pack_kernel, dim3(NIMG * HEIGHT / PACK_ROWS), dim3(256), 0,
                       stream, x, packed);
    hipLaunchKernelGGL(regmorph_kernel,
                       dim3(NIMG * WPR * NBANDS), dim3(64), 0, stream,
                       packed, out);
}

// Round 2
// 114.569 us; speedup vs baseline: 1.0030x; 1.0002x over previous
//
#include <hip/hip_runtime.h>
#include <stdint.h>

// Two-kernel binary-morphology skeleton (R8 structure + DPP shifts + RPL=1).
// Pack: float4 loads (all 4 issued up-front) + nibble + shfl_xor OR-reduce.
// Morph: wave-autonomous REGISTER morphology — lane i holds ONE row x 3 u64
// words (center output word + halo word each side). Vertical neighbors via
// DPP wave_shr1/wave_shl1 (1-cycle VALU, zero-fill at wave edge).
// RPL=1 rationale (R2): with RPL=2 only 2816 waves exist (2.75/SIMD) and all
// waves phase-lock — full 8-step compute (~6us aggregate) completes BEFORE
// any store issues (~11us aggregate) => morph ~= 17us serial instead of
// max(compute, store). RPL=1 gives 8960 waves (~8/SIMD with 2-wave blocks):
// 1.55x redundant-halo compute, but stores overlap compute via wave stagger
// and the 2nd residency batch pipelines behind the 1st.

typedef unsigned long long u64;
typedef float vfloat4 __attribute__((ext_vector_type(4)));

#define WIDTH   1024
#define HEIGHT  1024
#define NIMG    16
#define WPR     16          // u64 words per image row
#define RPL     1           // rows per lane
#define VROWS   64          // rows covered per wave = 64*RPL
#define HALO    17          // 8 steps x (erode+dilate) + iso conv
#define BVALID  30          // VROWS - 2*HALO
#define NBANDS  35          // ceil(1024/30)
#define MWAVES  2           // waves per morph block
#define PACK_ROWS 4

// ---------------- phase 1: binarize + bit-pack, float4 + shfl assembly -------
__global__ __launch_bounds__(256) void pack_kernel(const float* __restrict__ x,
                                                   u64* __restrict__ packed) {
    int wv = threadIdx.x >> 6, lane = threadIdx.x & 63;
    int row = blockIdx.x * PACK_ROWS + wv;        // one image row per wave
    const float* rbase = x + (size_t)row * WIDTH;
    u64* pbase = packed + (size_t)row * WPR;
    vfloat4 v[4];
    #pragma unroll
    for (int rnd = 0; rnd < 4; ++rnd)             // all 4 loads outstanding
        v[rnd] = *(const vfloat4*)(rbase + rnd * 256 + lane * 4);
    #pragma unroll
    for (int rnd = 0; rnd < 4; ++rnd) {           // 256 px per round
        unsigned nib = (v[rnd].x > 0.5f ? 1u : 0u) | (v[rnd].y > 0.5f ? 2u : 0u)
                     | (v[rnd].z > 0.5f ? 4u : 0u) | (v[rnd].w > 0.5f ? 8u : 0u);
        u64 n = (u64)nib << (4 * (lane & 15));
        n |= __shfl_xor(n, 1);                    // OR-reduce within 16-lane
        n |= __shfl_xor(n, 2);                    // groups: group g holds
        n |= __shfl_xor(n, 4);                    // px 256*rnd+64g..+63
        n |= __shfl_xor(n, 8);
        if ((lane & 15) == 0) pbase[rnd * 4 + (lane >> 4)] = n;
    }
}

// ---------------- wave-edge shifts via DPP (zero beyond wave = halo pad) -----
// WAVE_SHR1 (0x138): dst[i] = src[i-1]  -> value from lane above (sh_up)
// WAVE_SHL1 (0x130): dst[i] = src[i+1]  -> value from lane below (sh_dn)
// bound_ctrl=true: out-of-range source reads 0 (matches zero-pad semantics).
__device__ __forceinline__ u64 sh_up(u64 x, int lane) {
    (void)lane;
    unsigned lo = (unsigned)__builtin_amdgcn_update_dpp(
        0, (int)(unsigned)x, 0x138, 0xf, 0xf, true);
    unsigned hi = (unsigned)__builtin_amdgcn_update_dpp(
        0, (int)(unsigned)(x >> 32), 0x138, 0xf, 0xf, true);
    return ((u64)hi << 32) | lo;
}
__device__ __forceinline__ u64 sh_dn(u64 x, int lane) {
    (void)lane;
    unsigned lo = (unsigned)__builtin_amdgcn_update_dpp(
        0, (int)(unsigned)x, 0x130, 0xf, 0xf, true);
    unsigned hi = (unsigned)__builtin_amdgcn_update_dpp(
        0, (int)(unsigned)(x >> 32), 0x130, 0xf, 0xf, true);
    return ((u64)hi << 32) | lo;
}

// One skeleton step, fully in registers. Bit (LSB) = leftmost pixel.
// hand: CM&1 -> sample x-1 = (c<<1)|(left>>63); vand: RM&1 -> row above.
// Dilate uses reflected kernel (offsets negated). Proven mapping from R6/R8.
template <int RM, int CM, bool DIL>
__device__ __forceinline__ void mstep(u64 (&B)[RPL][3], u64 (&O)[RPL][3], int lane) {
    u64 T[RPL][3], M[RPL][3];
    // horizontal erode
    #pragma unroll
    for (int s = 0; s < RPL; ++s) {
        #pragma unroll
        for (int j = 0; j < 3; ++j) {
            u64 c = B[s][j], res = ~0ULL;
            if (CM & 2) res &= c;
            if (CM & 1) res &= (c << 1) | ((j > 0 ? B[s][j - 1] : 0ULL) >> 63);
            if (CM & 4) res &= (c >> 1) | ((j < 2 ? B[s][j + 1] : 0ULL) << 63);
            T[s][j] = res;
        }
    }
    // vertical erode -> M, O
    #pragma unroll
    for (int j = 0; j < 3; ++j) {
        u64 up = sh_up(T[RPL - 1][j], lane);
        u64 dn = sh_dn(T[0][j], lane);
        #pragma unroll
        for (int s = 0; s < RPL; ++s) {
            u64 res = ~0ULL;
            if (RM & 2) res &= T[s][j];
            if (RM & 1) res &= (s > 0 ? T[s - 1][j] : up);
            if (RM & 4) res &= (s < RPL - 1 ? T[s + 1][j] : dn);
            M[s][j] = res;
            O[s][j] |= res;
        }
    }
    if (DIL) {
        // horizontal dilate (reflected)
        #pragma unroll
        for (int s = 0; s < RPL; ++s) {
            #pragma unroll
            for (int j = 0; j < 3; ++j) {
                u64 c = M[s][j], res = 0;
                if (CM & 2) res |= c;
                if (CM & 1) res |= (c >> 1) | ((j < 2 ? M[s][j + 1] : 0ULL) << 63);
                if (CM & 4) res |= (c << 1) | ((j > 0 ? M[s][j - 1] : 0ULL) >> 63);
                T[s][j] = res;
            }
        }
        // vertical dilate (reflected), subtract from B
        #pragma unroll
        for (int j = 0; j < 3; ++j) {
            u64 up = sh_up(T[RPL - 1][j], lane);
            u64 dn = sh_dn(T[0][j], lane);
            #pragma unroll
            for (int s = 0; s < RPL; ++s) {
                u64 res = 0;
                if (RM & 2) res |= T[s][j];
                if (RM & 1) res |= (s < RPL - 1 ? T[s + 1][j] : dn);
                if (RM & 4) res |= (s > 0 ? T[s - 1][j] : up);
                B[s][j] &= ~res;
            }
        }
    }
}

// ---------------- phase 2: register morphology + isolated-point + expand -----
__global__ __launch_bounds__(64 * MWAVES) void regmorph_kernel(
        const u64* __restrict__ packed, float* __restrict__ out) {
    __shared__ u64 stage[MWAVES][BVALID + 2];
    int lane = threadIdx.x & 63;
    int wv = threadIdx.x >> 6;
    int W = blockIdx.x * MWAVES + wv;             // flat wave id, 0..8959
    int img  = W / (WPR * NBANDS);
    int rem  = W % (WPR * NBANDS);
    int wcol = rem / NBANDS;
    int band = rem % NBANDS;
    int bstart = band * BVALID - HALO;            // global row of v=0

    // load 1 row x 3 words per lane, zero outside image (zero-pad semantics)
    const u64* pimg = packed + (size_t)img * HEIGHT * WPR;
    u64 B[RPL][3], O[RPL][3];
    #pragma unroll
    for (int s = 0; s < RPL; ++s) {
        int g = bstart + lane * RPL + s;
        bool rok = (g >= 0 && g < HEIGHT);
        #pragma unroll
        for (int j = 0; j < 3; ++j) {
            int wi = wcol - 1 + j;
            B[s][j] = (rok && wi >= 0 && wi < WPR) ? pimg[(size_t)g * WPR + wi] : 0ULL;
            O[s][j] = 0ULL;
        }
    }

    // 8 structuring elements as (rowmask, colmask) rectangles
    mstep<7, 7, true >(B, O, lane);   // all ones
    mstep<7, 6, true >(B, O, lane);   // cols {1,2}
    mstep<3, 7, true >(B, O, lane);   // rows {0,1}
    mstep<6, 6, true >(B, O, lane);   // rows {1,2} x cols {1,2}
    mstep<7, 2, true >(B, O, lane);   // col {1}
    mstep<2, 7, true >(B, O, lane);   // row {1}
    mstep<3, 2, true >(B, O, lane);   // col {1}, rows {0,1}
    mstep<2, 3, false>(B, O, lane);   // row {1}, cols {0,1}; B unused after

    // isolated-point: 3x3 popcount of O == 1, center word only (carry-save)
    u64 Wn[RPL], Cn[RPL], En[RPL], res[RPL];
    #pragma unroll
    for (int s = 0; s < RPL; ++s) {
        Cn[s] = O[s][1];
        Wn[s] = (O[s][1] << 1) | (O[s][0] >> 63);
        En[s] = (O[s][1] >> 1) | (O[s][2] << 63);
    }
    u64 upW = sh_up(Wn[RPL - 1], lane), upC = sh_up(Cn[RPL - 1], lane),
        upE = sh_up(En[RPL - 1], lane);
    u64 dnW = sh_dn(Wn[0], lane), dnC = sh_dn(Cn[0], lane), dnE = sh_dn(En[0], lane);
    #pragma unroll
    for (int s = 0; s < RPL; ++s) {
        u64 ones = 0, twos = 0;
        auto acc = [&](u64 v) { twos |= ones & v; ones ^= v; };
        acc(s > 0 ? Wn[s - 1] : upW);
        acc(s > 0 ? Cn[s - 1] : upC);
        acc(s > 0 ? En[s - 1] : upE);
        acc(Wn[s]); acc(Cn[s]); acc(En[s]);
        acc(s < RPL - 1 ? Wn[s + 1] : dnW);
        acc(s < RPL - 1 ? Cn[s + 1] : dnC);
        acc(s < RPL - 1 ? En[s + 1] : dnE);
        res[s] = ones & ~twos;
    }

    // stage valid rows (v in [HALO, HALO+BVALID)) into this wave's LDS slice
    #pragma unroll
    for (int s = 0; s < RPL; ++s) {
        int v = lane * RPL + s;
        if (v >= HALO && v < HALO + BVALID) stage[wv][v - HALO] = res[s];
    }
    __syncthreads();   // orders LDS writes -> reads across the block

    // expand to f32, coalesced: per instr 4 rows x 16 lanes x 16 B (full lines)
    int gbase = band * BVALID;
    float* obase = out + (size_t)img * HEIGHT * WIDTH + wcol * 64 + (lane & 15) * 4;
    for (int it = 0; it < (BVALID + 3) / 4; ++it) {
        int t = it * 4 + (lane >> 4);
        int g = gbase + t;
        if (t < BVALID && g < HEIGHT) {
            u64 word = stage[wv][t];
            unsigned nib = (unsigned)(word >> ((lane & 15) * 4)) & 15u;
            vfloat4 v4;
            v4.x = (nib & 1) ? 1.f : 0.f;
            v4.y = (nib & 2) ? 1.f : 0.f;
            v4.z = (nib & 4) ? 1.f : 0.f;
            v4.w = (nib & 8) ? 1.f : 0.f;
            __builtin_nontemporal_store(v4, (vfloat4*)(obase + (size_t)g * WIDTH));
        }
    }
}

extern "C" void kernel_launch(void* const* d_in, const int* in_sizes, int n_in,
                              void* d_out, int out_size, void* d_ws, size_t ws_size,
                              hipStream_t stream) {
    const float* x = (const float*)d_in[0];
    float* out = (float*)d_out;
    u64* packed = (u64*)d_ws;   // NIMG*HEIGHT*WPR*8 = 2 MiB used

    hipLaunchKernelGGL(pack_kernel, dim3(NIMG * HEIGHT / PACK_ROWS), dim3(256), 0,
                       stream, x, packed);
    hipLaunchKernelGGL(regmorph_kernel,
                       dim3(NIMG * WPR * NBANDS / MWAVES), dim3(64 * MWAVES), 0,
                       stream, packed, out);
}